// Round 8
// baseline (24.264 us; speedup 1.0000x reference)
//
#include <hip/hip_runtime.h>
#include <math.h>

#define EPSN 1e-12f

typedef __attribute__((ext_vector_type(8))) __bf16 bf16x8;
typedef __attribute__((ext_vector_type(8))) short short8;
typedef __attribute__((ext_vector_type(4))) float floatx4;

static __device__ __forceinline__ unsigned short f2bf(float f) {
    return __builtin_bit_cast(unsigned short, (__bf16)f);
}

// ---------------------------------------------------------------------------
// Prep: blocks 0..63:  At[e][m][n] = bf16( A[e][n][m] )      (raw transpose)
//       blocks 64..67: rnorm[e][m] = 1/max(||A[e][:][m]||, eps)
// Norm folded OUT of At (applied in main epilogue: rnorm>0 commutes w/ relu).
// ---------------------------------------------------------------------------
__global__ __launch_bounds__(256)
void prep_kernel(const float* __restrict__ A, unsigned short* __restrict__ At,
                 float* __restrict__ rnorm) {
    __shared__ float Als[32][33];
    const int t = threadIdx.x, bid = blockIdx.x;
    if (bid < 64) {
        const int e  = bid >> 4;
        const int n0 = ((bid >> 2) & 3) * 32;
        const int m0 = (bid & 3) * 32;
        const float* Ae = A + e * 16384;
        #pragma unroll
        for (int i = 0; i < 4; ++i) {
            int nl = i * 8 + (t >> 5), ml = t & 31;
            Als[nl][ml] = Ae[(n0 + nl) * 128 + m0 + ml];   // coalesced in m
        }
        __syncthreads();
        int ml = t >> 3, nc = (t & 7) * 4;
        unsigned short hs[4] __attribute__((aligned(8)));
        #pragma unroll
        for (int j = 0; j < 4; ++j) hs[j] = f2bf(Als[nc + j][ml]);
        *(unsigned long long*)(At + ((size_t)(e * 128 + m0 + ml) * 128 + n0 + nc)) =
            *(const unsigned long long*)hs;
    } else {
        const int e = bid - 64;
        if (t < 128) {
            const float* Ae = A + e * 16384 + t;
            float s = 0.f;
            #pragma unroll 8
            for (int n = 0; n < 128; ++n) { float v = Ae[n * 128]; s += v * v; }
            rnorm[e * 128 + t] = 1.0f / fmaxf(sqrtf(s), EPSN);
        }
    }
}

// ---------------------------------------------------------------------------
// Main: grid 512 = (m-half h) x (bc-group of 8). 256 threads.
// Phase 1 (MFMA): XW[e][r=(bcl,o)][n] = bf16(x)@bf16(W) via 16x16x32 with
//   K zero-padded to 32 (lanes lg>=2 supply zero frags). 16 MFMA/wave.
//   D scatter -> LDS xw, XOR-swizzled with ((r&7)^(e<<1))<<4.
// Phase 2: wave e: 32r x 64m (half h), K=128; B-frags from At (raw-A bf16);
//   epilogue scales by rnorm[e][m], relu, coalesced float4 stores.
// ---------------------------------------------------------------------------
__global__ __launch_bounds__(256, 4)
void gcn_mfma_kernel(const float* __restrict__ x, const float* __restrict__ W,
                     const unsigned short* __restrict__ At,
                     const float* __restrict__ rnorm,
                     float* __restrict__ out) {
    __shared__ __align__(16) unsigned char xw[32768];  // 4e x 32r x 128n bf16

    const int t   = threadIdx.x;
    const int gid = blockIdx.x;
    const int h   = gid >> 8;          // m-half
    const int bc0 = (gid & 255) * 8;
    const int wv  = t >> 6;            // wave 0..3
    const int l   = t & 63;
    const int cl  = l & 15;            // A-row / B-col lane index
    const int lg  = l >> 4;            // k-group

    // ---- phase-1 B operand: W^T fragment, col=(e,o)=cl, k=lg*8+j (k<16 real)
    bf16x8 bW;
    {
        short8 z = {0, 0, 0, 0, 0, 0, 0, 0};
        bW = __builtin_bit_cast(bf16x8, z);
        if (lg < 2) {
            int eW = cl >> 2, oW = cl & 3;
            unsigned short hs[8] __attribute__((aligned(16)));
            #pragma unroll
            for (int j = 0; j < 8; ++j)
                hs[j] = f2bf(W[eW * 64 + (lg * 8 + j) * 4 + oW]);
            bW = __builtin_bit_cast(bf16x8, *(const short8*)hs);
        }
    }

    // ---- phase 1: 16 row-tiles of 16 rows per wave (1024 rows = 8bc x 128n)
    #pragma unroll
    for (int ti = 0; ti < 16; ++ti) {
        bf16x8 ax;
        { short8 z = {0, 0, 0, 0, 0, 0, 0, 0}; ax = __builtin_bit_cast(bf16x8, z); }
        if (lg < 2) {
            int g = wv * 256 + ti * 16 + cl;       // global row: bcl=g>>7, n=g&127
            const float* xp = x + ((size_t)(bc0 + (g >> 7)) * 128 + (g & 127)) * 16 + lg * 8;
            float4 v0 = *(const float4*)xp;
            float4 v1 = *(const float4*)(xp + 4);
            unsigned short hs[8] __attribute__((aligned(16)));
            hs[0] = f2bf(v0.x); hs[1] = f2bf(v0.y); hs[2] = f2bf(v0.z); hs[3] = f2bf(v0.w);
            hs[4] = f2bf(v1.x); hs[5] = f2bf(v1.y); hs[6] = f2bf(v1.z); hs[7] = f2bf(v1.w);
            ax = __builtin_bit_cast(bf16x8, *(const short8*)hs);
        }
        floatx4 d = {0.f, 0.f, 0.f, 0.f};
        d = __builtin_amdgcn_mfma_f32_16x16x32_bf16(ax, bW, d, 0, 0, 0);
        // D: col=cl=(e,o); row=lg*4+reg -> n = (ti&7)*16 + lg*4 + reg
        int eD = cl >> 2, oD = cl & 3;
        int rr = (wv * 2 + (ti >> 3)) * 4 + oD;    // xw row = bcl*4+o
        int nb = (ti & 7) * 16 + lg * 4;
        int base = (eD * 32 + rr) << 8;
        int s = (((rr & 7) ^ (eD << 1)) & 7) << 4;
        #pragma unroll
        for (int reg = 0; reg < 4; ++reg) {
            int byteoff = (base + (nb + reg) * 2) ^ s;
            *(unsigned short*)(xw + byteoff) = f2bf(d[reg]);
        }
    }
    __syncthreads();

    // ---- phase 2: wave = e; GEMM 32r x 64m (half h), K=128 ----
    const int e = wv;
    bf16x8 af[2][4];
    #pragma unroll
    for (int rt = 0; rt < 2; ++rt) {
        #pragma unroll
        for (int ks = 0; ks < 4; ++ks) {
            int row = rt * 16 + cl;
            int n0 = ks * 32 + lg * 8;
            int byteoff = (((e * 32 + row) << 8) + n0 * 2) ^
                          ((((row & 7) ^ (e << 1)) & 7) << 4);
            af[rt][ks] = __builtin_bit_cast(bf16x8, *(const short8*)(xw + byteoff));
        }
    }

    floatx4 acc[2][4];
    #pragma unroll
    for (int rt = 0; rt < 2; ++rt)
        #pragma unroll
        for (int mt = 0; mt < 4; ++mt)
            acc[rt][mt] = (floatx4){0.f, 0.f, 0.f, 0.f};

    const unsigned short* Ate = At + (size_t)e * 16384 + (size_t)h * 64 * 128;
    #pragma unroll
    for (int mt = 0; mt < 4; ++mt) {
        int m = mt * 16 + cl;
        bf16x8 bfr[4];
        #pragma unroll
        for (int ks = 0; ks < 4; ++ks)
            bfr[ks] = __builtin_bit_cast(bf16x8,
                *(const short8*)(Ate + (size_t)m * 128 + ks * 32 + lg * 8));
        #pragma unroll
        for (int ks = 0; ks < 4; ++ks) {
            acc[0][mt] = __builtin_amdgcn_mfma_f32_16x16x32_bf16(
                af[0][ks], bfr[ks], acc[0][mt], 0, 0, 0);
            acc[1][mt] = __builtin_amdgcn_mfma_f32_16x16x32_bf16(
                af[1][ks], bfr[ks], acc[1][mt], 0, 0, 0);
        }
    }

    // ---- epilogue: rnorm scale + relu. D col=cl (m-off); row=lg*4+j ->
    //      r = rt*16+lg*4+j -> bcl = rt*4+lg, o=j.
    float rnv[4];
    #pragma unroll
    for (int mt = 0; mt < 4; ++mt)
        rnv[mt] = rnorm[e * 128 + h * 64 + mt * 16 + cl];
    #pragma unroll
    for (int rt = 0; rt < 2; ++rt) {
        int bc = bc0 + rt * 4 + lg;
        int b = bc >> 4, c = bc & 15;
        float4* outp = (float4*)out + ((size_t)(b * 64 + e * 16 + c) * 128) + h * 64;
        #pragma unroll
        for (int mt = 0; mt < 4; ++mt) {
            float rn = rnv[mt];
            float4 o4;
            o4.x = fmaxf(acc[rt][mt][0] * rn, 0.f);
            o4.y = fmaxf(acc[rt][mt][1] * rn, 0.f);
            o4.z = fmaxf(acc[rt][mt][2] * rn, 0.f);
            o4.w = fmaxf(acc[rt][mt][3] * rn, 0.f);
            outp[mt * 16 + cl] = o4;
        }
    }
}

extern "C" void kernel_launch(void* const* d_in, const int* in_sizes, int n_in,
                              void* d_out, int out_size, void* d_ws, size_t ws_size,
                              hipStream_t stream) {
    const float* x = (const float*)d_in[0];   // [128,16,128,16]
    const float* A = (const float*)d_in[1];   // [4,128,128]
    const float* W = (const float*)d_in[2];   // [4,16,4]
    float* out = (float*)d_out;               // [128,64,128,4]
    unsigned short* At = (unsigned short*)d_ws;            // 128 KB (raw-A^T bf16)
    float* rnorm = (float*)((char*)d_ws + 131072);         // 512 f32

    prep_kernel<<<68, 256, 0, stream>>>(A, At, rnorm);
    gcn_mfma_kernel<<<512, 256, 0, stream>>>(x, W, At, rnorm, out);
}